// Round 21
// baseline (152.381 us; speedup 1.0000x reference)
//
#include <hip/hip_runtime.h>
#include <hip/hip_bf16.h>
#include <math.h>

typedef __attribute__((ext_vector_type(8))) short short8;
typedef __attribute__((ext_vector_type(4))) float f32x4;

// Problem constants: B=32, D=64, H=W=64, K=512
#define KC      512
#define DD      64
#define NROWS   131072
#define HWN     4096
#define BSTRIDE 262144
#define TOTELEM 8388608.0f
#define MARGIN  0.03f

// ---- workspace layout (float offsets) ----
#define WS_LOSSACC 0        // [1] f (pad 32)
#define WS_FLAGC   32       // [1] int (pad 64)
#define WS_CNTP    64       // [8*512] f count partials
#define WS_DWP     4160     // [8*64*512] f dw partials dwp[g][d][k]
#define WS_EMBT    266304   // [64*512] f embT[d][k]
#define WS_ENORM   299072   // [512] f
#define WS_IDX     299584   // [131072] int
#define WS_ROWBEST 430656   // [131072] f
#define WS_EHL     561728   // [65536] short (byte 2246912, 16B aligned)
#define WS_LIST    594496   // [131072] int
#define WS_ZERO_BYTES 1065216  // lossacc..dwp end (266304 floats)

// ---- output layout (float offsets) ----
#define OUT_QUANT 0
#define OUT_LOSS  8388608
#define OUT_PERP  8388609
#define OUT_EMB   8388610
#define OUT_SM    8421378
#define OUT_EMAW  8421890

// RNE float->bf16 split: v ~= hi + lo (each bf16), error ~2^-18 relative
__device__ __forceinline__ void bfsplit(float v, short& h, short& l) {
    unsigned u  = __float_as_uint(v);
    unsigned hb = (u + 0x7FFFu + ((u >> 16) & 1u)) & 0xFFFF0000u;
    h = (short)(hb >> 16);
    float lo = v - __uint_as_float(hb);
    unsigned u2 = __float_as_uint(lo);
    l = (short)((u2 + 0x7FFFu + ((u2 >> 16) & 1u)) >> 16);
}

// K0: fused prep — enorm (64-lane butterfly) + embT + bf16 hi/lo fragments.
__global__ void k_prep3(const float* __restrict__ emb, float* __restrict__ enorm,
                        short* __restrict__ ehl, float* __restrict__ embT) {
    const int w    = threadIdx.x >> 6;
    const int lane = threadIdx.x & 63;
    const int k    = blockIdx.x * 4 + w;
    const int d    = lane;
    float v = emb[k * DD + d];               // coalesced (DD == 64 == wave)
    float s = v * v;
#pragma unroll
    for (int o = 1; o < 64; o <<= 1) s += __shfl_xor(s, o);
    if (lane == 0) enorm[k] = s;
    embT[d * KC + k] = v;
    short hh, ll;
    bfsplit(v, hh, ll);
    int nt = k >> 4, cl = k & 15;
    int ks = d >> 5, q = (d & 31) >> 3, ii = d & 7;
    int fl = q * 16 + cl;
    ehl[((nt * 2 + ks) * 2 + 0) * 512 + fl * 8 + ii] = hh;
    ehl[((nt * 2 + ks) * 2 + 1) * 512 + fl * 8 + ii] = ll;
}

// K1: MFMA argmin + rowbest. argmax form with -enorm/2 folded into MFMA C-init.
// R21: 1 m-tile (16 rows) per wave, 2048 blocks, 8 waves/SIMD for latency hiding.
__global__ __launch_bounds__(256, 8) void k_argmin_mfma(
        const float* __restrict__ x, const short* __restrict__ ehl,
        const float* __restrict__ enorm, int* __restrict__ idx_out,
        float* __restrict__ rowbest, int* __restrict__ flagcnt,
        int* __restrict__ list) {
    const int tid  = threadIdx.x;
    const int w    = tid >> 6;
    const int lane = tid & 63;
    const int lm   = lane & 15, lq = lane >> 4;
    const int rowbase = blockIdx.x * 64 + w * 16;   // 16 rows per wave
    const int bb = rowbase >> 12, hw0 = rowbase & 4095;
    const float* xb = x + bb * BSTRIDE + hw0;

    short8 ah[2], al[2];
    float  fnj[4];
    {
        float xv[16];
#pragma unroll
        for (int ks = 0; ks < 2; ++ks)
#pragma unroll
            for (int i = 0; i < 8; ++i) {
                int d = ks * 32 + lq * 8 + i;
                xv[ks * 8 + i] = xb[d * HWN + lm];
            }
        float p0 = 0.f, p1 = 0.f, p2 = 0.f, p3 = 0.f;
#pragma unroll
        for (int t = 0; t < 16; t += 4) {
            p0 += xv[t] * xv[t];
            p1 += xv[t + 1] * xv[t + 1];
            p2 += xv[t + 2] * xv[t + 2];
            p3 += xv[t + 3] * xv[t + 3];
        }
        float fn = (p0 + p1) + (p2 + p3);
        fn += __shfl_xor(fn, 16);
        fn += __shfl_xor(fn, 32);
#pragma unroll
        for (int j = 0; j < 4; ++j) fnj[j] = __shfl(fn, lq * 4 + j);
#pragma unroll
        for (int ks = 0; ks < 2; ++ks) {
            short8 h8, l8;
#pragma unroll
            for (int i = 0; i < 8; ++i) {
                short hh, ll;
                bfsplit(xv[ks * 8 + i], hh, ll);
                h8[i] = hh; l8[i] = ll;
            }
            ah[ks] = h8; al[ks] = l8;
        }
    }

    const short8* eb = (const short8*)ehl;
    float smax[4], s2nd[4];
    int   bi[4];
#pragma unroll
    for (int j = 0; j < 4; ++j) { smax[j] = -3.4e38f; s2nd[j] = -3.4e38f; bi[j] = 0; }

    short8 nh0 = eb[0 * 64 + lane], nl0 = eb[1 * 64 + lane];
    short8 nh1 = eb[2 * 64 + lane], nl1 = eb[3 * 64 + lane];
#pragma unroll 2
    for (int nt = 0; nt < 32; ++nt) {
        short8 bh0 = nh0, bl0 = nl0, bh1 = nh1, bl1 = nl1;
        const int ntn = ((nt + 1) & 31) * 4;        // branchless wrapped prefetch
        nh0 = eb[(ntn + 0) * 64 + lane];
        nl0 = eb[(ntn + 1) * 64 + lane];
        nh1 = eb[(ntn + 2) * 64 + lane];
        nl1 = eb[(ntn + 3) * 64 + lane];
        const float nen2 = -0.5f * enorm[nt * 16 + lm];
        const int c = nt * 16 + lm;
        f32x4 acc = {nen2, nen2, nen2, nen2};       // C-init carries -enorm/2
        acc = __builtin_amdgcn_mfma_f32_16x16x32_bf16(ah[0], bh0, acc, 0, 0, 0);
        acc = __builtin_amdgcn_mfma_f32_16x16x32_bf16(al[0], bh0, acc, 0, 0, 0);
        acc = __builtin_amdgcn_mfma_f32_16x16x32_bf16(ah[0], bl0, acc, 0, 0, 0);
        acc = __builtin_amdgcn_mfma_f32_16x16x32_bf16(ah[1], bh1, acc, 0, 0, 0);
        acc = __builtin_amdgcn_mfma_f32_16x16x32_bf16(al[1], bh1, acc, 0, 0, 0);
        acc = __builtin_amdgcn_mfma_f32_16x16x32_bf16(ah[1], bl1, acc, 0, 0, 0);
#pragma unroll
        for (int j = 0; j < 4; ++j) {
            float s  = acc[j];                       // already dot - enorm/2
            bool  gt = s > smax[j];                  // strict >: first-max tie-break
            bi[j] = gt ? c : bi[j];
            // new 2nd-best = median{s, old smax, old s2nd} (since s2nd <= smax)
            asm("v_med3_f32 %0, %1, %2, %0"
                : "+v"(s2nd[j]) : "v"(s), "v"(smax[j]));
            smax[j] = fmaxf(s, smax[j]);
        }
    }

#pragma unroll
    for (int j = 0; j < 4; ++j) {
        float s = smax[j], s2 = s2nd[j];
        int   ii = bi[j];
#pragma unroll
        for (int o = 1; o < 16; o <<= 1) {
            float os  = __shfl_xor(s, o);
            float os2 = __shfl_xor(s2, o);
            int   oi  = __shfl_xor(ii, o);
            bool take = (os > s) || (os == s && oi < ii);
            float lose = take ? s : os;
            s2 = fmaxf(lose, fmaxf(s2, os2));
            s  = take ? os : s;
            ii = take ? oi : ii;
        }
        if (lm == 0) {
            int row = rowbase + lq * 4 + j;
            idx_out[row] = ii;
            rowbest[row] = fnj[j] - 2.0f * s;
            if (2.0f * (s - s2) < MARGIN) {
                int p = atomicAdd(flagcnt, 1);
                list[p] = row;
            }
        }
    }
}

// K2: exact fp32 re-argmin for flagged rows (patches idx + rowbest).
__global__ void k_refine(const float* __restrict__ x, const float* __restrict__ emb,
                         const float* __restrict__ enorm, const int* __restrict__ list,
                         const int* __restrict__ flagcnt, int* __restrict__ idx_out,
                         float* __restrict__ rowbest) {
    const int gw   = (blockIdx.x * 256 + threadIdx.x) >> 6;
    const int lane = threadIdx.x & 63;
    const int nw   = gridDim.x * 4;
    const int total = *flagcnt;
    for (int t = gw; t < total; t += nw) {
        int row = list[t];
        int b = row >> 12, hw = row & 4095;
        const float* xp = x + b * BSTRIDE + hw;
        float r[64];
#pragma unroll
        for (int d = 0; d < 64; ++d) r[d] = xp[d * HWN];
        float f0 = 0.f, f1 = 0.f, f2 = 0.f, f3 = 0.f;
#pragma unroll
        for (int d = 0; d < 64; d += 4) {
            f0 += r[d] * r[d]; f1 += r[d + 1] * r[d + 1];
            f2 += r[d + 2] * r[d + 2]; f3 += r[d + 3] * r[d + 3];
        }
        float fn = (f0 + f1) + (f2 + f3);
        float best = 3.4e38f; int bi = 0;
        for (int c0 = 0; c0 < 8; ++c0) {
            int k = c0 * 64 + lane;
            const float* e = emb + k * DD;
            float a0 = 0.f, a1 = 0.f, a2 = 0.f, a3 = 0.f;
#pragma unroll
            for (int d = 0; d < 64; d += 4) {
                a0 += r[d] * e[d]; a1 += r[d + 1] * e[d + 1];
                a2 += r[d + 2] * e[d + 2]; a3 += r[d + 3] * e[d + 3];
            }
            float dist = fn - 2.0f * ((a0 + a1) + (a2 + a3)) + enorm[k];
            if (dist < best) { best = dist; bi = k; }
        }
#pragma unroll
        for (int o = 1; o < 64; o <<= 1) {
            float ob = __shfl_xor(best, o);
            int   oi = __shfl_xor(bi, o);
            if (ob < best || (ob == best && oi < bi)) { best = ob; bi = oi; }
        }
        if (lane == 0) { idx_out[row] = bi; rowbest[row] = best; }
    }
}

// K3: combined quant + dw. XCD-swizzled decode: b = bid&31, d = bid>>5.
__global__ __launch_bounds__(256) void k_scatter(
        const float* __restrict__ x, const float* __restrict__ embT,
        const int* __restrict__ idx, float* __restrict__ qout,
        float* __restrict__ dwp) {
    __shared__ float dwloc[KC];
    __shared__ float ecol[KC];
    const int bid = blockIdx.x;
    const int b = bid & 31, d = bid >> 5;   // XCD-aligned decode
    const int tid = threadIdx.x;            // 256

    for (int i = tid; i < KC; i += 256) {
        dwloc[i] = 0.f;
        ecol[i]  = embT[d * KC + i];
    }

    const float4* xp4 = (const float4*)(x + b * BSTRIDE + d * HWN);
    float4*       qp4 = (float4*)(qout + b * BSTRIDE + d * HWN);
    const int4*   ip4 = (const int4*)(idx + b * HWN);

    float4 xv0 = xp4[tid];
    float4 xv1 = xp4[256 + tid];
    float4 xv2 = xp4[512 + tid];
    float4 xv3 = xp4[768 + tid];
    int4   iv0 = ip4[tid];
    int4   iv1 = ip4[256 + tid];
    int4   iv2 = ip4[512 + tid];
    int4   iv3 = ip4[768 + tid];
    __syncthreads();

    float4 q0, q1, q2, q3;
    q0.x = ecol[iv0.x]; q0.y = ecol[iv0.y]; q0.z = ecol[iv0.z]; q0.w = ecol[iv0.w];
    q1.x = ecol[iv1.x]; q1.y = ecol[iv1.y]; q1.z = ecol[iv1.z]; q1.w = ecol[iv1.w];
    q2.x = ecol[iv2.x]; q2.y = ecol[iv2.y]; q2.z = ecol[iv2.z]; q2.w = ecol[iv2.w];
    q3.x = ecol[iv3.x]; q3.y = ecol[iv3.y]; q3.z = ecol[iv3.z]; q3.w = ecol[iv3.w];
    qp4[tid]       = q0;
    qp4[256 + tid] = q1;
    qp4[512 + tid] = q2;
    qp4[768 + tid] = q3;

    atomicAdd(&dwloc[iv0.x], xv0.x); atomicAdd(&dwloc[iv0.y], xv0.y);
    atomicAdd(&dwloc[iv0.z], xv0.z); atomicAdd(&dwloc[iv0.w], xv0.w);
    atomicAdd(&dwloc[iv1.x], xv1.x); atomicAdd(&dwloc[iv1.y], xv1.y);
    atomicAdd(&dwloc[iv1.z], xv1.z); atomicAdd(&dwloc[iv1.w], xv1.w);
    atomicAdd(&dwloc[iv2.x], xv2.x); atomicAdd(&dwloc[iv2.y], xv2.y);
    atomicAdd(&dwloc[iv2.z], xv2.z); atomicAdd(&dwloc[iv2.w], xv2.w);
    atomicAdd(&dwloc[iv3.x], xv3.x); atomicAdd(&dwloc[iv3.y], xv3.y);
    atomicAdd(&dwloc[iv3.z], xv3.z); atomicAdd(&dwloc[iv3.w], xv3.w);
    __syncthreads();

    float* dp = dwp + ((b & 7) * DD + d) * KC;
    for (int i = tid; i < KC; i += 256)
        atomicAdd(&dp[i], dwloc[i]);   // 4 contenders, all same XCD
}

// K4: counts histogram + loss sum (from idx/rowbest, grid-stride, 64 blocks).
__global__ void k_histloss(const int* __restrict__ idx,
                           const float* __restrict__ rowbest,
                           float* __restrict__ cntp, float* __restrict__ lossacc) {
    __shared__ float h[KC];
    __shared__ float red[4];
    const int tid = threadIdx.x;   // 256
    for (int i = tid; i < KC; i += 256) h[i] = 0.f;
    __syncthreads();
    const int stride = gridDim.x * 256;
    float ls = 0.f;
    for (int t = blockIdx.x * 256 + tid; t < NROWS / 4; t += stride) {
        int4 iv = ((const int4*)idx)[t];
        atomicAdd(&h[iv.x], 1.f); atomicAdd(&h[iv.y], 1.f);
        atomicAdd(&h[iv.z], 1.f); atomicAdd(&h[iv.w], 1.f);
        float4 rv = ((const float4*)rowbest)[t];
        ls += (rv.x + rv.y) + (rv.z + rv.w);
    }
#pragma unroll
    for (int o = 32; o > 0; o >>= 1) ls += __shfl_down(ls, o);
    if ((tid & 63) == 0) red[tid >> 6] = ls;
    __syncthreads();
    if (tid == 0) atomicAdd(lossacc, (red[0] + red[1]) + (red[2] + red[3]));
    float* cp = cntp + (blockIdx.x & 7) * KC;
    for (int i = tid; i < KC; i += 256) {
        float v = h[i];
        if (v != 0.f) atomicAdd(&cp[i], v);   // integer-valued: exact
    }
}

// K5: fused final + emb (128 blocks; redundant deterministic n/es per block).
__global__ void k_embfinal(const float* __restrict__ cntp,
                           const float* __restrict__ ema_cs,
                           const float* __restrict__ lossacc,
                           const float* __restrict__ ema_w,
                           const float* __restrict__ dwp,
                           float* __restrict__ out) {
    __shared__ float rn[4], re[4];
    __shared__ float nb;
    const int tid = threadIdx.x;   // 256

    float n_part = 0.f, e_part = 0.f;
#pragma unroll
    for (int r = 0; r < 2; ++r) {
        int code = r * 256 + tid;
        float c = 0.f;
#pragma unroll
        for (int g = 0; g < 8; ++g) c += cntp[g * KC + code];
        n_part += 0.99f * ema_cs[code] + 0.01f * c;
        float p = c * (1.0f / 131072.0f);
        e_part += (p > 0.f) ? p * logf(p) : 0.f;
    }
#pragma unroll
    for (int o = 32; o > 0; o >>= 1) {
        n_part += __shfl_down(n_part, o);
        e_part += __shfl_down(e_part, o);
    }
    if ((tid & 63) == 0) { rn[tid >> 6] = n_part; re[tid >> 6] = e_part; }
    __syncthreads();
    if (tid == 0) {
        nb = (rn[0] + rn[1]) + (rn[2] + rn[3]);
        if (blockIdx.x == 0) {
            float es = (re[0] + re[1]) + (re[2] + re[3]);
            out[OUT_LOSS] = 0.25f * (lossacc[0] / TOTELEM);
            out[OUT_PERP] = expf(-es);
        }
    }
    __syncthreads();
    const float n = nb;

    const int i = blockIdx.x * 256 + tid;   // i = k*64 + d
    const int k = i >> 6, d = i & 63;
    float ck = 0.f;
#pragma unroll
    for (int g = 0; g < 8; ++g) ck += cntp[g * KC + k];   // wave-uniform: broadcast
    float ncsk = 0.99f * ema_cs[k] + 0.01f * ck;
    float smk  = (ncsk + 1e-5f) / (n + 0.00512f) * n;
    if ((tid & 63) == 0) out[OUT_SM + k] = smk;

    float dw = 0.f;
#pragma unroll
    for (int g = 0; g < 8; ++g) dw += dwp[(g * DD + d) * KC + k];
    float nw = 0.99f * ema_w[i] + 0.01f * dw;
    out[OUT_EMAW + i] = nw;
    out[OUT_EMB + i]  = nw / smk;
}

extern "C" void kernel_launch(void* const* d_in, const int* in_sizes, int n_in,
                              void* d_out, int out_size, void* d_ws, size_t ws_size,
                              hipStream_t stream) {
    const float* x      = (const float*)d_in[0];
    const float* emb    = (const float*)d_in[1];
    const float* ema_cs = (const float*)d_in[2];
    const float* ema_w  = (const float*)d_in[3];
    float* out = (float*)d_out;

    float* wsf     = (float*)d_ws;
    float* lossacc = wsf + WS_LOSSACC;
    int*   flagcnt = (int*)(wsf + WS_FLAGC);
    float* cntp    = wsf + WS_CNTP;
    float* dwp     = wsf + WS_DWP;
    float* embT    = wsf + WS_EMBT;
    float* enorm   = wsf + WS_ENORM;
    int*   idx     = (int*)(wsf + WS_IDX);
    float* rowbest = wsf + WS_ROWBEST;
    short* ehl     = (short*)(wsf + WS_EHL);
    int*   list    = (int*)(wsf + WS_LIST);

    hipMemsetAsync(d_ws, 0, WS_ZERO_BYTES, stream);

    k_prep3      <<<128,  256, 0, stream>>>(emb, enorm, ehl, embT);
    k_argmin_mfma<<<2048, 256, 0, stream>>>(x, ehl, enorm, idx, rowbest, flagcnt, list);
    k_refine     <<<256,  256, 0, stream>>>(x, emb, enorm, list, flagcnt, idx, rowbest);
    k_scatter    <<<2048, 256, 0, stream>>>(x, embT, idx, out + OUT_QUANT, dwp);
    k_histloss   <<<64,   256, 0, stream>>>(idx, rowbest, cntp, lossacc);
    k_embfinal   <<<128,  256, 0, stream>>>(cntp, ema_cs, lossacc, ema_w, dwp, out);
}

// Round 22
// 126.622 us; speedup vs baseline: 1.2034x; 1.2034x over previous
//
#include <hip/hip_runtime.h>
#include <hip/hip_bf16.h>
#include <math.h>

typedef __attribute__((ext_vector_type(8))) short short8;
typedef __attribute__((ext_vector_type(4))) float f32x4;

// Problem constants: B=32, D=64, H=W=64, K=512
#define KC      512
#define DD      64
#define NROWS   131072
#define HWN     4096
#define BSTRIDE 262144
#define TOTELEM 8388608.0f
#define MARGIN  0.03f

// ---- workspace layout (float offsets) ----
#define WS_LOSSACC 0        // [1] f (pad 32)
#define WS_FLAGC   32       // [1] int (pad 64)
#define WS_CNTP    64       // [8*512] f count partials
#define WS_DWP     4160     // [8*64*512] f dw partials dwp[g][d][k]
#define WS_EMBT    266304   // [64*512] f embT[d][k]
#define WS_ENORM   299072   // [512] f
#define WS_IDX     299584   // [131072] int
#define WS_ROWBEST 430656   // [131072] f
#define WS_EHL     561728   // [65536] short (byte 2246912, 16B aligned)
#define WS_LIST    594496   // [131072] int
#define WS_ZERO_BYTES 1065216  // lossacc..dwp end (266304 floats)

// ---- output layout (float offsets) ----
#define OUT_QUANT 0
#define OUT_LOSS  8388608
#define OUT_PERP  8388609
#define OUT_EMB   8388610
#define OUT_SM    8421378
#define OUT_EMAW  8421890

// RNE float->bf16 split: v ~= hi + lo (each bf16), error ~2^-18 relative
__device__ __forceinline__ void bfsplit(float v, short& h, short& l) {
    unsigned u  = __float_as_uint(v);
    unsigned hb = (u + 0x7FFFu + ((u >> 16) & 1u)) & 0xFFFF0000u;
    h = (short)(hb >> 16);
    float lo = v - __uint_as_float(hb);
    unsigned u2 = __float_as_uint(lo);
    l = (short)((u2 + 0x7FFFu + ((u2 >> 16) & 1u)) >> 16);
}

// K0: fused prep — enorm (64-lane butterfly) + embT + bf16 hi/lo fragments.
__global__ void k_prep3(const float* __restrict__ emb, float* __restrict__ enorm,
                        short* __restrict__ ehl, float* __restrict__ embT) {
    const int w    = threadIdx.x >> 6;
    const int lane = threadIdx.x & 63;
    const int k    = blockIdx.x * 4 + w;
    const int d    = lane;
    float v = emb[k * DD + d];               // coalesced (DD == 64 == wave)
    float s = v * v;
#pragma unroll
    for (int o = 1; o < 64; o <<= 1) s += __shfl_xor(s, o);
    if (lane == 0) enorm[k] = s;
    embT[d * KC + k] = v;
    short hh, ll;
    bfsplit(v, hh, ll);
    int nt = k >> 4, cl = k & 15;
    int ks = d >> 5, q = (d & 31) >> 3, ii = d & 7;
    int fl = q * 16 + cl;
    ehl[((nt * 2 + ks) * 2 + 0) * 512 + fl * 8 + ii] = hh;
    ehl[((nt * 2 + ks) * 2 + 1) * 512 + fl * 8 + ii] = ll;
}

// K1: MFMA argmin + rowbest. argmax form with -enorm/2 folded into MFMA C-init.
// R22 = R20 config (measured optimum): 2 m-tiles (32 rows)/wave, 1024 blocks.
// m-tile sweep measured: 4mt=46.3us, 2mt=43-44us, 1mt=68us (L2-traffic bound).
__global__ __launch_bounds__(256, 4) void k_argmin_mfma(
        const float* __restrict__ x, const short* __restrict__ ehl,
        const float* __restrict__ enorm, int* __restrict__ idx_out,
        float* __restrict__ rowbest, int* __restrict__ flagcnt,
        int* __restrict__ list) {
    const int tid  = threadIdx.x;
    const int w    = tid >> 6;
    const int lane = tid & 63;
    const int lm   = lane & 15, lq = lane >> 4;
    const int rowbase = blockIdx.x * 128 + w * 32;
    const int bb = rowbase >> 12, hw0 = rowbase & 4095;
    const float* xb = x + bb * BSTRIDE + hw0;

    short8 ah[2][2], al[2][2];
    float  fnj[2][4];
#pragma unroll
    for (int mt = 0; mt < 2; ++mt) {
        float xv[16];
#pragma unroll
        for (int ks = 0; ks < 2; ++ks)
#pragma unroll
            for (int i = 0; i < 8; ++i) {
                int d = ks * 32 + lq * 8 + i;
                xv[ks * 8 + i] = xb[d * HWN + mt * 16 + lm];
            }
        float p0 = 0.f, p1 = 0.f, p2 = 0.f, p3 = 0.f;
#pragma unroll
        for (int t = 0; t < 16; t += 4) {
            p0 += xv[t] * xv[t];
            p1 += xv[t + 1] * xv[t + 1];
            p2 += xv[t + 2] * xv[t + 2];
            p3 += xv[t + 3] * xv[t + 3];
        }
        float fn = (p0 + p1) + (p2 + p3);
        fn += __shfl_xor(fn, 16);
        fn += __shfl_xor(fn, 32);
#pragma unroll
        for (int j = 0; j < 4; ++j) fnj[mt][j] = __shfl(fn, lq * 4 + j);
#pragma unroll
        for (int ks = 0; ks < 2; ++ks) {
            short8 h8, l8;
#pragma unroll
            for (int i = 0; i < 8; ++i) {
                short hh, ll;
                bfsplit(xv[ks * 8 + i], hh, ll);
                h8[i] = hh; l8[i] = ll;
            }
            ah[mt][ks] = h8; al[mt][ks] = l8;
        }
    }

    const short8* eb = (const short8*)ehl;
    float smax[2][4], s2nd[2][4];
    int   bi[2][4];
#pragma unroll
    for (int mt = 0; mt < 2; ++mt)
#pragma unroll
        for (int j = 0; j < 4; ++j) { smax[mt][j] = -3.4e38f; s2nd[mt][j] = -3.4e38f; bi[mt][j] = 0; }

    short8 nh0 = eb[0 * 64 + lane], nl0 = eb[1 * 64 + lane];
    short8 nh1 = eb[2 * 64 + lane], nl1 = eb[3 * 64 + lane];
#pragma unroll 2
    for (int nt = 0; nt < 32; ++nt) {
        short8 bh0 = nh0, bl0 = nl0, bh1 = nh1, bl1 = nl1;
        const int ntn = ((nt + 1) & 31) * 4;        // branchless wrapped prefetch
        nh0 = eb[(ntn + 0) * 64 + lane];
        nl0 = eb[(ntn + 1) * 64 + lane];
        nh1 = eb[(ntn + 2) * 64 + lane];
        nl1 = eb[(ntn + 3) * 64 + lane];
        const float nen2 = -0.5f * enorm[nt * 16 + lm];
        const int c = nt * 16 + lm;
#pragma unroll
        for (int mt = 0; mt < 2; ++mt) {
            f32x4 acc = {nen2, nen2, nen2, nen2};   // C-init carries -enorm/2
            acc = __builtin_amdgcn_mfma_f32_16x16x32_bf16(ah[mt][0], bh0, acc, 0, 0, 0);
            acc = __builtin_amdgcn_mfma_f32_16x16x32_bf16(al[mt][0], bh0, acc, 0, 0, 0);
            acc = __builtin_amdgcn_mfma_f32_16x16x32_bf16(ah[mt][0], bl0, acc, 0, 0, 0);
            acc = __builtin_amdgcn_mfma_f32_16x16x32_bf16(ah[mt][1], bh1, acc, 0, 0, 0);
            acc = __builtin_amdgcn_mfma_f32_16x16x32_bf16(al[mt][1], bh1, acc, 0, 0, 0);
            acc = __builtin_amdgcn_mfma_f32_16x16x32_bf16(ah[mt][1], bl1, acc, 0, 0, 0);
#pragma unroll
            for (int j = 0; j < 4; ++j) {
                float s  = acc[j];                   // already dot - enorm/2
                bool  gt = s > smax[mt][j];          // strict >: first-max tie-break
                bi[mt][j] = gt ? c : bi[mt][j];
                // new 2nd-best = median{s, old smax, old s2nd} (since s2nd <= smax)
                asm("v_med3_f32 %0, %1, %2, %0"
                    : "+v"(s2nd[mt][j]) : "v"(s), "v"(smax[mt][j]));
                smax[mt][j] = fmaxf(s, smax[mt][j]);
            }
        }
    }

#pragma unroll
    for (int mt = 0; mt < 2; ++mt)
#pragma unroll
        for (int j = 0; j < 4; ++j) {
            float s = smax[mt][j], s2 = s2nd[mt][j];
            int   ii = bi[mt][j];
#pragma unroll
            for (int o = 1; o < 16; o <<= 1) {
                float os  = __shfl_xor(s, o);
                float os2 = __shfl_xor(s2, o);
                int   oi  = __shfl_xor(ii, o);
                bool take = (os > s) || (os == s && oi < ii);
                float lose = take ? s : os;
                s2 = fmaxf(lose, fmaxf(s2, os2));
                s  = take ? os : s;
                ii = take ? oi : ii;
            }
            if (lm == 0) {
                int row = rowbase + mt * 16 + lq * 4 + j;
                idx_out[row] = ii;
                rowbest[row] = fnj[mt][j] - 2.0f * s;
                if (2.0f * (s - s2) < MARGIN) {
                    int p = atomicAdd(flagcnt, 1);
                    list[p] = row;
                }
            }
        }
}

// K2: exact fp32 re-argmin for flagged rows (patches idx + rowbest).
__global__ void k_refine(const float* __restrict__ x, const float* __restrict__ emb,
                         const float* __restrict__ enorm, const int* __restrict__ list,
                         const int* __restrict__ flagcnt, int* __restrict__ idx_out,
                         float* __restrict__ rowbest) {
    const int gw   = (blockIdx.x * 256 + threadIdx.x) >> 6;
    const int lane = threadIdx.x & 63;
    const int nw   = gridDim.x * 4;
    const int total = *flagcnt;
    for (int t = gw; t < total; t += nw) {
        int row = list[t];
        int b = row >> 12, hw = row & 4095;
        const float* xp = x + b * BSTRIDE + hw;
        float r[64];
#pragma unroll
        for (int d = 0; d < 64; ++d) r[d] = xp[d * HWN];
        float f0 = 0.f, f1 = 0.f, f2 = 0.f, f3 = 0.f;
#pragma unroll
        for (int d = 0; d < 64; d += 4) {
            f0 += r[d] * r[d]; f1 += r[d + 1] * r[d + 1];
            f2 += r[d + 2] * r[d + 2]; f3 += r[d + 3] * r[d + 3];
        }
        float fn = (f0 + f1) + (f2 + f3);
        float best = 3.4e38f; int bi = 0;
        for (int c0 = 0; c0 < 8; ++c0) {
            int k = c0 * 64 + lane;
            const float* e = emb + k * DD;
            float a0 = 0.f, a1 = 0.f, a2 = 0.f, a3 = 0.f;
#pragma unroll
            for (int d = 0; d < 64; d += 4) {
                a0 += r[d] * e[d]; a1 += r[d + 1] * e[d + 1];
                a2 += r[d + 2] * e[d + 2]; a3 += r[d + 3] * e[d + 3];
            }
            float dist = fn - 2.0f * ((a0 + a1) + (a2 + a3)) + enorm[k];
            if (dist < best) { best = dist; bi = k; }
        }
#pragma unroll
        for (int o = 1; o < 64; o <<= 1) {
            float ob = __shfl_xor(best, o);
            int   oi = __shfl_xor(bi, o);
            if (ob < best || (ob == best && oi < bi)) { best = ob; bi = oi; }
        }
        if (lane == 0) { idx_out[row] = bi; rowbest[row] = best; }
    }
}

// K3: combined quant + dw. XCD-swizzled decode: b = bid&31, d = bid>>5.
__global__ __launch_bounds__(256) void k_scatter(
        const float* __restrict__ x, const float* __restrict__ embT,
        const int* __restrict__ idx, float* __restrict__ qout,
        float* __restrict__ dwp) {
    __shared__ float dwloc[KC];
    __shared__ float ecol[KC];
    const int bid = blockIdx.x;
    const int b = bid & 31, d = bid >> 5;   // XCD-aligned decode
    const int tid = threadIdx.x;            // 256

    for (int i = tid; i < KC; i += 256) {
        dwloc[i] = 0.f;
        ecol[i]  = embT[d * KC + i];
    }

    const float4* xp4 = (const float4*)(x + b * BSTRIDE + d * HWN);
    float4*       qp4 = (float4*)(qout + b * BSTRIDE + d * HWN);
    const int4*   ip4 = (const int4*)(idx + b * HWN);

    float4 xv0 = xp4[tid];
    float4 xv1 = xp4[256 + tid];
    float4 xv2 = xp4[512 + tid];
    float4 xv3 = xp4[768 + tid];
    int4   iv0 = ip4[tid];
    int4   iv1 = ip4[256 + tid];
    int4   iv2 = ip4[512 + tid];
    int4   iv3 = ip4[768 + tid];
    __syncthreads();

    float4 q0, q1, q2, q3;
    q0.x = ecol[iv0.x]; q0.y = ecol[iv0.y]; q0.z = ecol[iv0.z]; q0.w = ecol[iv0.w];
    q1.x = ecol[iv1.x]; q1.y = ecol[iv1.y]; q1.z = ecol[iv1.z]; q1.w = ecol[iv1.w];
    q2.x = ecol[iv2.x]; q2.y = ecol[iv2.y]; q2.z = ecol[iv2.z]; q2.w = ecol[iv2.w];
    q3.x = ecol[iv3.x]; q3.y = ecol[iv3.y]; q3.z = ecol[iv3.z]; q3.w = ecol[iv3.w];
    qp4[tid]       = q0;
    qp4[256 + tid] = q1;
    qp4[512 + tid] = q2;
    qp4[768 + tid] = q3;

    atomicAdd(&dwloc[iv0.x], xv0.x); atomicAdd(&dwloc[iv0.y], xv0.y);
    atomicAdd(&dwloc[iv0.z], xv0.z); atomicAdd(&dwloc[iv0.w], xv0.w);
    atomicAdd(&dwloc[iv1.x], xv1.x); atomicAdd(&dwloc[iv1.y], xv1.y);
    atomicAdd(&dwloc[iv1.z], xv1.z); atomicAdd(&dwloc[iv1.w], xv1.w);
    atomicAdd(&dwloc[iv2.x], xv2.x); atomicAdd(&dwloc[iv2.y], xv2.y);
    atomicAdd(&dwloc[iv2.z], xv2.z); atomicAdd(&dwloc[iv2.w], xv2.w);
    atomicAdd(&dwloc[iv3.x], xv3.x); atomicAdd(&dwloc[iv3.y], xv3.y);
    atomicAdd(&dwloc[iv3.z], xv3.z); atomicAdd(&dwloc[iv3.w], xv3.w);
    __syncthreads();

    float* dp = dwp + ((b & 7) * DD + d) * KC;
    for (int i = tid; i < KC; i += 256)
        atomicAdd(&dp[i], dwloc[i]);   // 4 contenders, all same XCD
}

// K4: counts histogram + loss sum (from idx/rowbest, grid-stride, 64 blocks).
__global__ void k_histloss(const int* __restrict__ idx,
                           const float* __restrict__ rowbest,
                           float* __restrict__ cntp, float* __restrict__ lossacc) {
    __shared__ float h[KC];
    __shared__ float red[4];
    const int tid = threadIdx.x;   // 256
    for (int i = tid; i < KC; i += 256) h[i] = 0.f;
    __syncthreads();
    const int stride = gridDim.x * 256;
    float ls = 0.f;
    for (int t = blockIdx.x * 256 + tid; t < NROWS / 4; t += stride) {
        int4 iv = ((const int4*)idx)[t];
        atomicAdd(&h[iv.x], 1.f); atomicAdd(&h[iv.y], 1.f);
        atomicAdd(&h[iv.z], 1.f); atomicAdd(&h[iv.w], 1.f);
        float4 rv = ((const float4*)rowbest)[t];
        ls += (rv.x + rv.y) + (rv.z + rv.w);
    }
#pragma unroll
    for (int o = 32; o > 0; o >>= 1) ls += __shfl_down(ls, o);
    if ((tid & 63) == 0) red[tid >> 6] = ls;
    __syncthreads();
    if (tid == 0) atomicAdd(lossacc, (red[0] + red[1]) + (red[2] + red[3]));
    float* cp = cntp + (blockIdx.x & 7) * KC;
    for (int i = tid; i < KC; i += 256) {
        float v = h[i];
        if (v != 0.f) atomicAdd(&cp[i], v);   // integer-valued: exact
    }
}

// K5: fused final + emb (128 blocks; redundant deterministic n/es per block).
__global__ void k_embfinal(const float* __restrict__ cntp,
                           const float* __restrict__ ema_cs,
                           const float* __restrict__ lossacc,
                           const float* __restrict__ ema_w,
                           const float* __restrict__ dwp,
                           float* __restrict__ out) {
    __shared__ float rn[4], re[4];
    __shared__ float nb;
    const int tid = threadIdx.x;   // 256

    float n_part = 0.f, e_part = 0.f;
#pragma unroll
    for (int r = 0; r < 2; ++r) {
        int code = r * 256 + tid;
        float c = 0.f;
#pragma unroll
        for (int g = 0; g < 8; ++g) c += cntp[g * KC + code];
        n_part += 0.99f * ema_cs[code] + 0.01f * c;
        float p = c * (1.0f / 131072.0f);
        e_part += (p > 0.f) ? p * logf(p) : 0.f;
    }
#pragma unroll
    for (int o = 32; o > 0; o >>= 1) {
        n_part += __shfl_down(n_part, o);
        e_part += __shfl_down(e_part, o);
    }
    if ((tid & 63) == 0) { rn[tid >> 6] = n_part; re[tid >> 6] = e_part; }
    __syncthreads();
    if (tid == 0) {
        nb = (rn[0] + rn[1]) + (rn[2] + rn[3]);
        if (blockIdx.x == 0) {
            float es = (re[0] + re[1]) + (re[2] + re[3]);
            out[OUT_LOSS] = 0.25f * (lossacc[0] / TOTELEM);
            out[OUT_PERP] = expf(-es);
        }
    }
    __syncthreads();
    const float n = nb;

    const int i = blockIdx.x * 256 + tid;   // i = k*64 + d
    const int k = i >> 6, d = i & 63;
    float ck = 0.f;
#pragma unroll
    for (int g = 0; g < 8; ++g) ck += cntp[g * KC + k];   // wave-uniform: broadcast
    float ncsk = 0.99f * ema_cs[k] + 0.01f * ck;
    float smk  = (ncsk + 1e-5f) / (n + 0.00512f) * n;
    if ((tid & 63) == 0) out[OUT_SM + k] = smk;

    float dw = 0.f;
#pragma unroll
    for (int g = 0; g < 8; ++g) dw += dwp[(g * DD + d) * KC + k];
    float nw = 0.99f * ema_w[i] + 0.01f * dw;
    out[OUT_EMAW + i] = nw;
    out[OUT_EMB + i]  = nw / smk;
}

extern "C" void kernel_launch(void* const* d_in, const int* in_sizes, int n_in,
                              void* d_out, int out_size, void* d_ws, size_t ws_size,
                              hipStream_t stream) {
    const float* x      = (const float*)d_in[0];
    const float* emb    = (const float*)d_in[1];
    const float* ema_cs = (const float*)d_in[2];
    const float* ema_w  = (const float*)d_in[3];
    float* out = (float*)d_out;

    float* wsf     = (float*)d_ws;
    float* lossacc = wsf + WS_LOSSACC;
    int*   flagcnt = (int*)(wsf + WS_FLAGC);
    float* cntp    = wsf + WS_CNTP;
    float* dwp     = wsf + WS_DWP;
    float* embT    = wsf + WS_EMBT;
    float* enorm   = wsf + WS_ENORM;
    int*   idx     = (int*)(wsf + WS_IDX);
    float* rowbest = wsf + WS_ROWBEST;
    short* ehl     = (short*)(wsf + WS_EHL);
    int*   list    = (int*)(wsf + WS_LIST);

    hipMemsetAsync(d_ws, 0, WS_ZERO_BYTES, stream);

    k_prep3      <<<128,  256, 0, stream>>>(emb, enorm, ehl, embT);
    k_argmin_mfma<<<1024, 256, 0, stream>>>(x, ehl, enorm, idx, rowbest, flagcnt, list);
    k_refine     <<<256,  256, 0, stream>>>(x, emb, enorm, list, flagcnt, idx, rowbest);
    k_scatter    <<<2048, 256, 0, stream>>>(x, embT, idx, out + OUT_QUANT, dwp);
    k_histloss   <<<64,   256, 0, stream>>>(idx, rowbest, cntp, lossacc);
    k_embfinal   <<<128,  256, 0, stream>>>(cntp, ema_cs, lossacc, ema_w, dwp, out);
}